// Round 4
// baseline (83.802 us; speedup 1.0000x reference)
//
#include <hip/hip_runtime.h>
#include <math.h>

// Problem constants (fixed by setup_inputs: N=8, C=3, ph=pw=256, S=1024)
#define S   1024
#define PH  256
#define NP  8

// Native clang vector type: valid for __builtin_nontemporal_store (HIP's
// float4 is a HIP_vector_type class and is rejected by the builtin).
typedef float f32x4 __attribute__((ext_vector_type(4)));

// V2b: 4 pixels per thread (same row), 16B streaming loads/stores.
//  - img/out moved as f32x4 (16B/lane) -> 4x fewer streaming mem instrs,
//    4x fewer waves (4096), nontemporal store (out is never re-read).
//  - y-dependent interp state (gy,py,floor,wy*,iy*,row bounds) hoisted:
//    identical for the 4 pixels of a thread, bitwise-same ops as reference.
//  - per-pixel x path keeps the exact __f*_rn op order of the reference so
//    results stay bit-exact (absmax must remain 0.0).
// Reference semantics replicated:
//   mask canvas is all-ones over the padded 1024^2 canvas; mask value is the
//   weight-sum over taps with iy/ix >= 0 (upper bound 1024 unreachable in the
//   pruned region); patch transparent unless mask == 1.0f exactly.
//   patch taps nonzero only inside [0,256)^2; composite: nonzero overwrites,
//   patches in order i=0..7.
__global__ __launch_bounds__(256)
void PatchTransformer_kernel(const float* __restrict__ adv,   // [8,3,256,256]
                             const float* __restrict__ loc,   // [8,2]
                             const float* __restrict__ img,   // [3,1024,1024]
                             float* __restrict__ out)         // [3,1024,1024]
{
    const int t = blockIdx.x * blockDim.x + threadIdx.x;   // 0 .. 262143
    if (t >= (S * S) / 4) return;
    const int idx4 = t << 2;                 // first pixel linear index
    const int w0 = idx4 & (S - 1);           // 4 px always within one row
    const int h  = idx4 >> 10;

    // normalized grid coords, exact op order of reference
    const float yn = __fsub_rn(__fdiv_rn(__fmul_rn(__fadd_rn((float)h, 0.5f), 2.0f), (float)S), 1.0f);
    float xn[4];
    #pragma unroll
    for (int j = 0; j < 4; ++j)
        xn[j] = __fsub_rn(__fdiv_rn(__fmul_rn(__fadd_rn((float)(w0 + j), 0.5f), 2.0f), (float)S), 1.0f);

    // streaming load of the 3 channel planes as 16B vectors
    const f32x4* img4 = reinterpret_cast<const f32x4*>(img);
    const int PLANE4 = (S * S) / 4;
    const f32x4 i0 = img4[t];
    const f32x4 i1 = img4[t + PLANE4];
    const f32x4 i2 = img4[t + 2 * PLANE4];
    float c0[4] = { i0.x, i0.y, i0.z, i0.w };
    float c1[4] = { i1.x, i1.y, i1.z, i1.w };
    float c2[4] = { i2.x, i2.y, i2.z, i2.w };

    #pragma unroll
    for (int i = 0; i < NP; ++i) {
        const float tx = loc[2 * i + 0];
        const float ty = loc[2 * i + 1];

        // ---- y path: identical for all 4 pixels of this thread ----
        const float gy = __fsub_rn(yn, ty);
        const float py = __fmul_rn(__fsub_rn(__fmul_rn(__fadd_rn(gy, 1.0f), (float)S), 1.0f), 0.5f);
        // Outside (-1, 256) in y: every tap of this patch is transparent for
        // this whole row -> skip the patch entirely.
        if (py <= -1.0f || py >= (float)PH) continue;

        const float y0f = floorf(py);
        const float wy1 = __fsub_rn(py, y0f);
        const float wy0 = __fsub_rn(1.0f, wy1);
        const int iy0 = (int)y0f, iy1 = iy0 + 1;     // iy0 in [-1,255]
        const bool my0 = (iy0 >= 0);                 // canvas validity (y)
        const bool by0 = my0;                        // iy0 < PH guaranteed (py<256)
        const bool by1 = (iy1 < PH);
        const int rb0 = iy0 * PH;
        const int rb1 = iy1 * PH;
        const float* advi = adv + (size_t)i * 3 * PH * PH;

        #pragma unroll
        for (int j = 0; j < 4; ++j) {
            const float gx = __fsub_rn(xn[j], tx);
            const float px = __fmul_rn(__fsub_rn(__fmul_rn(__fadd_rn(gx, 1.0f), (float)S), 1.0f), 0.5f);
            if (px <= -1.0f || px >= (float)PH) continue;

            const float x0f = floorf(px);
            const float wx1 = __fsub_rn(px, x0f);
            const float wx0 = __fsub_rn(1.0f, wx1);
            const float p00 = __fmul_rn(wy0, wx0);
            const float p01 = __fmul_rn(wy0, wx1);
            const float p10 = __fmul_rn(wy1, wx0);
            const float p11 = __fmul_rn(wy1, wx1);

            const int ix0 = (int)x0f, ix1 = ix0 + 1; // ix0 in [-1,255], ix1 in [0,256]

            // mask canvas (all-ones, 1024 wide): taps valid iff index >= 0
            const float m00 = (my0 && ix0 >= 0) ? 1.0f : 0.0f;
            const float m01 = my0 ? 1.0f : 0.0f;
            const float m10 = (ix0 >= 0) ? 1.0f : 0.0f;
            const float m11 = 1.0f;
            const float mval =
                __fadd_rn(__fadd_rn(__fadd_rn(__fmul_rn(m00, p00),
                                              __fmul_rn(m01, p01)),
                                    __fmul_rn(m10, p10)),
                          __fmul_rn(m11, p11));
            // mask != 1 -> patch_w = val*0 = +-0 -> transparent -> skip (exact)
            if (mval != 1.0f) continue;

            // padded-canvas patch tap is nonzero only inside [0,256)^2
            const bool bx0 = (ix0 >= 0);             // ix0 < PH guaranteed (px<256)
            const bool bx1 = (ix1 < PH);
            const int o00 = rb0 + ix0;
            const int o01 = rb0 + ix1;
            const int o10 = rb1 + ix0;
            const int o11 = rb1 + ix1;

            #pragma unroll
            for (int c = 0; c < 3; ++c) {
                const float* a = advi + c * PH * PH;
                const float g00 = (by0 && bx0) ? a[o00] : 0.0f;
                const float g01 = (by0 && bx1) ? a[o01] : 0.0f;
                const float g10 = (by1 && bx0) ? a[o10] : 0.0f;
                const float g11 = (by1 && bx1) ? a[o11] : 0.0f;
                const float val =
                    __fadd_rn(__fadd_rn(__fadd_rn(__fmul_rn(g00, p00),
                                                  __fmul_rn(g01, p01)),
                                        __fmul_rn(g10, p10)),
                          __fmul_rn(g11, p11));
                if (val != 0.0f) {
                    if (c == 0)      c0[j] = val;
                    else if (c == 1) c1[j] = val;
                    else             c2[j] = val;
                }
            }
        }
    }

    // streaming 16B stores, nontemporal (out is never re-read)
    f32x4* out4 = reinterpret_cast<f32x4*>(out);
    f32x4 o0, o1, o2;
    o0.x = c0[0]; o0.y = c0[1]; o0.z = c0[2]; o0.w = c0[3];
    o1.x = c1[0]; o1.y = c1[1]; o1.z = c1[2]; o1.w = c1[3];
    o2.x = c2[0]; o2.y = c2[1]; o2.z = c2[2]; o2.w = c2[3];
    __builtin_nontemporal_store(o0, out4 + t);
    __builtin_nontemporal_store(o1, out4 + t + PLANE4);
    __builtin_nontemporal_store(o2, out4 + t + 2 * PLANE4);
}

extern "C" void kernel_launch(void* const* d_in, const int* in_sizes, int n_in,
                              void* d_out, int out_size, void* d_ws, size_t ws_size,
                              hipStream_t stream) {
    const float* adv = (const float*)d_in[0];   // (8,3,256,256) f32
    const float* loc = (const float*)d_in[1];   // (8,2) f32
    const float* img = (const float*)d_in[2];   // (3,1024,1024) f32
    float* out = (float*)d_out;                 // (1,3,1024,1024) f32

    dim3 block(256);
    dim3 grid(((S * S) / 4 + 255) / 256);       // 1024 blocks
    hipLaunchKernelGGL(PatchTransformer_kernel, grid, block, 0, stream,
                       adv, loc, img, out);
}

// Round 5
// 81.442 us; speedup vs baseline: 1.0290x; 1.0290x over previous
//
#include <hip/hip_runtime.h>
#include <math.h>

// Problem constants (fixed by setup_inputs: N=8, C=3, ph=pw=256, S=1024)
#define S   1024
#define PH  256
#define NP  8

// Native clang vector type: valid for __builtin_nontemporal_store (HIP's
// float2 is a HIP_vector_type class and is rejected by the builtin).
typedef float f32x2 __attribute__((ext_vector_type(2)));

// V2c: 2 pixels per thread (same row), 8B streaming loads/stores.
// Lesson from V2b (4 px/thread): waves dropped to 16/CU (half the 32/CU cap)
// and the latency-bound kernel got ~17% slower. 2 px/thread keeps exactly
// 32 waves/CU (8192 waves) while still halving streaming vmem instructions
// (6M -> 3M) and doubling per-thread gather ILP.
//  - y-dependent interp state hoisted once per patch (identical for both px,
//    bitwise-same ops as reference).
//  - per-pixel x path keeps the exact __f*_rn op order of the reference.
// Reference semantics replicated:
//   mask canvas is all-ones over the padded 1024^2 canvas; mask value is the
//   weight-sum over taps with iy/ix >= 0 (upper bound 1024 unreachable in the
//   pruned region); patch transparent unless mask == 1.0f exactly.
//   patch taps nonzero only inside [0,256)^2; composite: nonzero overwrites,
//   patches in order i=0..7.
__global__ __launch_bounds__(256)
void PatchTransformer_kernel(const float* __restrict__ adv,   // [8,3,256,256]
                             const float* __restrict__ loc,   // [8,2]
                             const float* __restrict__ img,   // [3,1024,1024]
                             float* __restrict__ out)         // [3,1024,1024]
{
    const int t = blockIdx.x * blockDim.x + threadIdx.x;   // 0 .. 524287
    if (t >= (S * S) / 2) return;
    const int idx2 = t << 1;                 // first pixel linear index
    const int w0 = idx2 & (S - 1);           // 2 px always within one row
    const int h  = idx2 >> 10;

    // normalized grid coords, exact op order of reference
    const float yn = __fsub_rn(__fdiv_rn(__fmul_rn(__fadd_rn((float)h, 0.5f), 2.0f), (float)S), 1.0f);
    float xn[2];
    #pragma unroll
    for (int j = 0; j < 2; ++j)
        xn[j] = __fsub_rn(__fdiv_rn(__fmul_rn(__fadd_rn((float)(w0 + j), 0.5f), 2.0f), (float)S), 1.0f);

    // streaming load of the 3 channel planes as 8B vectors
    const f32x2* img2 = reinterpret_cast<const f32x2*>(img);
    const int PLANE2 = (S * S) / 2;
    const f32x2 i0 = img2[t];
    const f32x2 i1 = img2[t + PLANE2];
    const f32x2 i2 = img2[t + 2 * PLANE2];
    float c0[2] = { i0.x, i0.y };
    float c1[2] = { i1.x, i1.y };
    float c2[2] = { i2.x, i2.y };

    #pragma unroll
    for (int i = 0; i < NP; ++i) {
        const float tx = loc[2 * i + 0];
        const float ty = loc[2 * i + 1];

        // ---- y path: identical for both pixels of this thread ----
        const float gy = __fsub_rn(yn, ty);
        const float py = __fmul_rn(__fsub_rn(__fmul_rn(__fadd_rn(gy, 1.0f), (float)S), 1.0f), 0.5f);
        // Outside (-1, 256) in y: every tap of this patch is transparent for
        // this whole row -> skip the patch entirely.
        if (py <= -1.0f || py >= (float)PH) continue;

        const float y0f = floorf(py);
        const float wy1 = __fsub_rn(py, y0f);
        const float wy0 = __fsub_rn(1.0f, wy1);
        const int iy0 = (int)y0f, iy1 = iy0 + 1;     // iy0 in [-1,255]
        const bool my0 = (iy0 >= 0);                 // canvas validity (y)
        const bool by0 = my0;                        // iy0 < PH guaranteed (py<256)
        const bool by1 = (iy1 < PH);
        const int rb0 = iy0 * PH;
        const int rb1 = iy1 * PH;
        const float* advi = adv + (size_t)i * 3 * PH * PH;

        #pragma unroll
        for (int j = 0; j < 2; ++j) {
            const float gx = __fsub_rn(xn[j], tx);
            const float px = __fmul_rn(__fsub_rn(__fmul_rn(__fadd_rn(gx, 1.0f), (float)S), 1.0f), 0.5f);
            if (px <= -1.0f || px >= (float)PH) continue;

            const float x0f = floorf(px);
            const float wx1 = __fsub_rn(px, x0f);
            const float wx0 = __fsub_rn(1.0f, wx1);
            const float p00 = __fmul_rn(wy0, wx0);
            const float p01 = __fmul_rn(wy0, wx1);
            const float p10 = __fmul_rn(wy1, wx0);
            const float p11 = __fmul_rn(wy1, wx1);

            const int ix0 = (int)x0f, ix1 = ix0 + 1; // ix0 in [-1,255], ix1 in [0,256]

            // mask canvas (all-ones, 1024 wide): taps valid iff index >= 0
            const float m00 = (my0 && ix0 >= 0) ? 1.0f : 0.0f;
            const float m01 = my0 ? 1.0f : 0.0f;
            const float m10 = (ix0 >= 0) ? 1.0f : 0.0f;
            const float m11 = 1.0f;
            const float mval =
                __fadd_rn(__fadd_rn(__fadd_rn(__fmul_rn(m00, p00),
                                              __fmul_rn(m01, p01)),
                                    __fmul_rn(m10, p10)),
                          __fmul_rn(m11, p11));
            // mask != 1 -> patch_w = val*0 = +-0 -> transparent -> skip (exact)
            if (mval != 1.0f) continue;

            // padded-canvas patch tap is nonzero only inside [0,256)^2
            const bool bx0 = (ix0 >= 0);             // ix0 < PH guaranteed (px<256)
            const bool bx1 = (ix1 < PH);
            const int o00 = rb0 + ix0;
            const int o01 = rb0 + ix1;
            const int o10 = rb1 + ix0;
            const int o11 = rb1 + ix1;

            #pragma unroll
            for (int c = 0; c < 3; ++c) {
                const float* a = advi + c * PH * PH;
                const float g00 = (by0 && bx0) ? a[o00] : 0.0f;
                const float g01 = (by0 && bx1) ? a[o01] : 0.0f;
                const float g10 = (by1 && bx0) ? a[o10] : 0.0f;
                const float g11 = (by1 && bx1) ? a[o11] : 0.0f;
                const float val =
                    __fadd_rn(__fadd_rn(__fadd_rn(__fmul_rn(g00, p00),
                                                  __fmul_rn(g01, p01)),
                                        __fmul_rn(g10, p10)),
                              __fmul_rn(g11, p11));
                if (val != 0.0f) {
                    if (c == 0)      c0[j] = val;
                    else if (c == 1) c1[j] = val;
                    else             c2[j] = val;
                }
            }
        }
    }

    // streaming 8B stores, nontemporal (out is never re-read)
    f32x2* out2 = reinterpret_cast<f32x2*>(out);
    f32x2 o0, o1, o2;
    o0.x = c0[0]; o0.y = c0[1];
    o1.x = c1[0]; o1.y = c1[1];
    o2.x = c2[0]; o2.y = c2[1];
    __builtin_nontemporal_store(o0, out2 + t);
    __builtin_nontemporal_store(o1, out2 + t + PLANE2);
    __builtin_nontemporal_store(o2, out2 + t + 2 * PLANE2);
}

extern "C" void kernel_launch(void* const* d_in, const int* in_sizes, int n_in,
                              void* d_out, int out_size, void* d_ws, size_t ws_size,
                              hipStream_t stream) {
    const float* adv = (const float*)d_in[0];   // (8,3,256,256) f32
    const float* loc = (const float*)d_in[1];   // (8,2) f32
    const float* img = (const float*)d_in[2];   // (3,1024,1024) f32
    float* out = (float*)d_out;                 // (1,3,1024,1024) f32

    dim3 block(256);
    dim3 grid(((S * S) / 2 + 255) / 256);       // 2048 blocks
    hipLaunchKernelGGL(PatchTransformer_kernel, grid, block, 0, stream,
                       adv, loc, img, out);
}

// Round 6
// 79.307 us; speedup vs baseline: 1.0567x; 1.0269x over previous
//
#include <hip/hip_runtime.h>
#include <math.h>

// Problem constants (fixed by setup_inputs: N=8, C=3, ph=pw=256, S=1024)
#define S   1024
#define PH  256
#define NP  8

// V3: back to 1 px/thread (measured best: 1px 35us < 2px 39 < 4px 41 kernel
// time -> kernel is latency/TLP-bound, 16384 waves is the winning config).
// Two changes vs baseline, both latency-targeted, zero TLP cost:
//  1) img loads are NONTEMPORAL and LAZY: deferred until after the patch
//     loop and skipped entirely when all 3 channels were patch-covered
//     (patch values are ~never exactly 0, so covered => opaque). out stores
//     nontemporal. Keeps the 25 MB stream out of L2 so the 6.3 MB patch
//     working set stays L2-resident for the gather chains (4 MB/XCD).
//  2) gather loads stay normal (cacheable) - they are the reuse path.
// Per-pixel FP chain is op-for-op identical to the reference (__f*_rn,
// no contraction), so absmax should be 0.0 (2^-8 seen on rounds 4/5 is
// suspected node-side; this near-baseline structure is the diagnostic).
__global__ __launch_bounds__(256)
void PatchTransformer_kernel(const float* __restrict__ adv,   // [8,3,256,256]
                             const float* __restrict__ loc,   // [8,2]
                             const float* __restrict__ img,   // [3,1024,1024]
                             float* __restrict__ out)         // [3,1024,1024]
{
    const int idx = blockIdx.x * blockDim.x + threadIdx.x;
    if (idx >= S * S) return;
    const int w = idx & (S - 1);
    const int h = idx >> 10;

    // normalized grid coords, exact op order of reference
    const float xn = __fsub_rn(__fdiv_rn(__fmul_rn(__fadd_rn((float)w, 0.5f), 2.0f), (float)S), 1.0f);
    const float yn = __fsub_rn(__fdiv_rn(__fmul_rn(__fadd_rn((float)h, 0.5f), 2.0f), (float)S), 1.0f);

    // patch composite accumulators; img filled in lazily afterwards
    float v0 = 0.0f, v1 = 0.0f, v2 = 0.0f;
    bool s0 = false, s1 = false, s2 = false;

    #pragma unroll
    for (int i = 0; i < NP; ++i) {
        const float tx = loc[2 * i + 0];
        const float ty = loc[2 * i + 1];
        const float gx = __fsub_rn(xn, tx);
        const float gy = __fsub_rn(yn, ty);
        const float px = __fmul_rn(__fsub_rn(__fmul_rn(__fadd_rn(gx, 1.0f), (float)S), 1.0f), 0.5f);
        const float py = __fmul_rn(__fsub_rn(__fmul_rn(__fadd_rn(gy, 1.0f), (float)S), 1.0f), 0.5f);

        // Outside (-1, 256)^2 every patch tap is exactly 0 -> transparent -> skip.
        if (px <= -1.0f || px >= (float)PH || py <= -1.0f || py >= (float)PH) continue;

        const float x0f = floorf(px), y0f = floorf(py);
        const float wx1 = __fsub_rn(px, x0f);
        const float wy1 = __fsub_rn(py, y0f);
        const float wx0 = __fsub_rn(1.0f, wx1);
        const float wy0 = __fsub_rn(1.0f, wy1);
        const float p00 = __fmul_rn(wy0, wx0);
        const float p01 = __fmul_rn(wy0, wx1);
        const float p10 = __fmul_rn(wy1, wx0);
        const float p11 = __fmul_rn(wy1, wx1);

        const int ix0 = (int)x0f, iy0 = (int)y0f;   // in [-1, 255]
        const int ix1 = ix0 + 1,  iy1 = iy0 + 1;    // in [0, 256]

        // mask canvas (all-ones, 1024 wide): taps valid iff index >= 0
        // (upper bound 1024 unreachable in the pruned region)
        const float m00 = (iy0 >= 0 && ix0 >= 0) ? 1.0f : 0.0f;
        const float m01 = (iy0 >= 0)             ? 1.0f : 0.0f;
        const float m10 = (ix0 >= 0)             ? 1.0f : 0.0f;
        const float m11 = 1.0f;
        const float mval =
            __fadd_rn(__fadd_rn(__fadd_rn(__fmul_rn(m00, p00),
                                          __fmul_rn(m01, p01)),
                                __fmul_rn(m10, p10)),
                      __fmul_rn(m11, p11));
        // mask != 1 -> patch_w = val*0 = +-0 -> transparent -> skip (exact)
        if (mval != 1.0f) continue;

        // padded-canvas patch tap is nonzero only inside [0,256)^2
        const bool bx0 = (ix0 >= 0) && (ix0 < PH);
        const bool bx1 = (ix1 < PH);
        const bool by0 = (iy0 >= 0) && (iy0 < PH);
        const bool by1 = (iy1 < PH);
        const int o00 = iy0 * PH + ix0;
        const int o01 = iy0 * PH + ix1;
        const int o10 = iy1 * PH + ix0;
        const int o11 = iy1 * PH + ix1;
        const float* advi = adv + (size_t)i * 3 * PH * PH;

        #pragma unroll
        for (int c = 0; c < 3; ++c) {
            const float* a = advi + c * PH * PH;
            const float g00 = (by0 && bx0) ? a[o00] : 0.0f;
            const float g01 = (by0 && bx1) ? a[o01] : 0.0f;
            const float g10 = (by1 && bx0) ? a[o10] : 0.0f;
            const float g11 = (by1 && bx1) ? a[o11] : 0.0f;
            const float val =
                __fadd_rn(__fadd_rn(__fadd_rn(__fmul_rn(g00, p00),
                                              __fmul_rn(g01, p01)),
                                    __fmul_rn(g10, p10)),
                          __fmul_rn(g11, p11));
            if (val != 0.0f) {
                if (c == 0)      { v0 = val; s0 = true; }
                else if (c == 1) { v1 = val; s1 = true; }
                else             { v2 = val; s2 = true; }
            }
        }
    }

    // Lazy background fill: only load img for channels no patch covered.
    // Nontemporal: img is read exactly once per pixel -> keep it out of L2
    // so the patch working set (6.3 MB) stays L2-resident.
    if (!(s0 && s1 && s2)) {
        if (!s0) v0 = __builtin_nontemporal_load(img + idx);
        if (!s1) v1 = __builtin_nontemporal_load(img + idx + S * S);
        if (!s2) v2 = __builtin_nontemporal_load(img + idx + 2 * S * S);
    }

    // nontemporal stores: out is never re-read
    __builtin_nontemporal_store(v0, out + idx);
    __builtin_nontemporal_store(v1, out + idx + S * S);
    __builtin_nontemporal_store(v2, out + idx + 2 * S * S);
}

extern "C" void kernel_launch(void* const* d_in, const int* in_sizes, int n_in,
                              void* d_out, int out_size, void* d_ws, size_t ws_size,
                              hipStream_t stream) {
    const float* adv = (const float*)d_in[0];   // (8,3,256,256) f32
    const float* loc = (const float*)d_in[1];   // (8,2) f32
    const float* img = (const float*)d_in[2];   // (3,1024,1024) f32
    float* out = (float*)d_out;                 // (1,3,1024,1024) f32

    dim3 block(256);
    dim3 grid((S * S + 255) / 256);             // 4096 blocks, 1 px/thread
    hipLaunchKernelGGL(PatchTransformer_kernel, grid, block, 0, stream,
                       adv, loc, img, out);
}